// Round 1
// baseline (420.528 us; speedup 1.0000x reference)
//
#include <hip/hip_runtime.h>

typedef unsigned short u16;
typedef __attribute__((ext_vector_type(8))) short short8;
typedef __attribute__((ext_vector_type(4))) float f32x4;

#define MFMA16(a, b, c) __builtin_amdgcn_mfma_f32_16x16x32_bf16((a), (b), (c), 0, 0, 0)

__device__ __forceinline__ u16 f2b(float f) {
  unsigned b = __float_as_uint(f);
  b += 0x7FFFu + ((b >> 16) & 1u);
  return (u16)(b >> 16);
}
__device__ __forceinline__ float b2f(u16 u) { return __uint_as_float(((unsigned)u) << 16); }

__device__ __forceinline__ void gload_lds16(const void* g, void* l) {
  __builtin_amdgcn_global_load_lds((const __attribute__((address_space(1))) void*)g,
                                   (__attribute__((address_space(3))) void*)l, 16, 0, 0);
}

// ---------------- small setup kernels ----------------
__global__ __launch_bounds__(256) void f2bf_kernel(const float* __restrict__ s,
                                                   u16* __restrict__ d, int n) {
  int i = blockIdx.x * 256 + threadIdx.x;
  if (i < n) d[i] = f2b(s[i]);
}

// bias_full[h][n][m] = table[rel_index[n*64+m]*8 + h], 8*4096 entries
__global__ __launch_bounds__(256) void biasfull_kernel(const float* __restrict__ tbl,
                                                       const int* __restrict__ ridx,
                                                       float* __restrict__ o) {
  int i = blockIdx.x * 256 + threadIdx.x;
  int hm = i >> 12, nm = i & 4095;
  o[i] = tbl[ridx[nm] * 8 + hm];
}

// ---------------- K1: LN1 + window partition -> Y bf16 [65536][256] ----------------
__global__ __launch_bounds__(256) void ln1_win_kernel(const float* __restrict__ x,
                                                      const float* __restrict__ g,
                                                      const float* __restrict__ b,
                                                      u16* __restrict__ y) {
  __shared__ u16 tile[64][260];  // pad 4 elems: stride 520B -> 2-way banks (free)
  __shared__ float ps_[64][4], pss_[64][4];
  __shared__ float mean_s[64], rstd_s[64];
  const int win = blockIdx.x;                    // b*64 + wy*8 + wx
  const int bb = win >> 6, wy = (win >> 3) & 7, wx = win & 7;
  const int t = threadIdx.x;
  const int tx = t & 7, ty = (t >> 3) & 7, cq = t >> 6;
  const int tok = ty * 8 + tx;
  const int h = wy * 8 + ty, w = wx * 8 + tx;
  const float* xp = x + (size_t)bb * 1048576 + (size_t)h * 64 + w;  // x[bb][0][h][w]
  float s = 0.f, ss = 0.f;
#pragma unroll 8
  for (int i = 0; i < 64; ++i) {
    int c = cq * 64 + i;
    float v = xp[(size_t)c * 4096];
    tile[tok][c] = f2b(v);
    s += v;
    ss += v * v;
  }
  ps_[tok][cq] = s;
  pss_[tok][cq] = ss;
  __syncthreads();
  if (t < 64) {
    float s4 = ps_[t][0] + ps_[t][1] + ps_[t][2] + ps_[t][3];
    float q4 = pss_[t][0] + pss_[t][1] + pss_[t][2] + pss_[t][3];
    float m = s4 * (1.f / 256.f);
    float var = q4 * (1.f / 256.f) - m * m;
    mean_s[t] = m;
    rstd_s[t] = rsqrtf(var + 1e-5f);
  }
  __syncthreads();
  const float gc = g[t], bc = b[t];  // t == channel here
  u16* yp = y + (size_t)win * 16384 + t;
#pragma unroll 4
  for (int k = 0; k < 64; ++k) {
    float v = b2f(tile[k][t]);
    yp[(size_t)k * 256] = f2b((v - mean_s[k]) * rstd_s[k] * gc + bc);
  }
}

// ---------------- GEMM: out = A[M x K] * W[N x K]^T + bias, bf16 in / MFMA ----------------
// EPI 0: qkv scatter (+q scale).  1: proj + x residual -> xs2 fp32.
// EPI 2: fc1 + exact GELU -> bf16. 3: fc2 + xs2 residual -> d_out BCHW fp32.
template <int EPI>
__global__ __launch_bounds__(256) void gemm_bt(const u16* __restrict__ A,
                                               const u16* __restrict__ W,
                                               const float* __restrict__ bias,
                                               u16* __restrict__ outh,
                                               float* __restrict__ outf,
                                               const float* __restrict__ aux,
                                               const int N, const int K) {
  __shared__ __align__(16) u16 As[128 * 64];
  __shared__ __align__(16) u16 Bs[128 * 64];
  const int ntiles = N >> 7;
  const int mt = blockIdx.x / ntiles;
  const int nt = blockIdx.x - mt * ntiles;
  const int tid = threadIdx.x;
  const int wv = tid >> 6, lane = tid & 63;
  const int wr = (wv >> 1) << 6;  // wave row quadrant
  const int wc = (wv & 1) << 6;   // wave col quadrant
  const int lrow = lane >> 3, lk = (lane & 7) << 3;
  const int lr = lane & 15, lg = lane >> 4;
  f32x4 acc[4][4];
#pragma unroll
  for (int mi = 0; mi < 4; ++mi)
#pragma unroll
    for (int ni = 0; ni < 4; ++ni) acc[mi][ni] = (f32x4){0.f, 0.f, 0.f, 0.f};
  const u16* Ab = A + (size_t)mt * 128 * K;
  const u16* Wb = W + (size_t)nt * 128 * K;
  for (int kt = 0; kt < K; kt += 64) {
#pragma unroll
    for (int i = 0; i < 4; ++i) {
      const int rb = wv * 32 + i * 8;
      gload_lds16(Ab + (size_t)(rb + lrow) * K + kt + lk, &As[rb * 64]);
    }
#pragma unroll
    for (int i = 0; i < 4; ++i) {
      const int rb = wv * 32 + i * 8;
      gload_lds16(Wb + (size_t)(rb + lrow) * K + kt + lk, &Bs[rb * 64]);
    }
    __syncthreads();
#pragma unroll
    for (int kk = 0; kk < 2; ++kk) {
      const int ko = kk * 32 + lg * 8;
      short8 a[4], bq[4];
#pragma unroll
      for (int mi = 0; mi < 4; ++mi) a[mi] = *(const short8*)&As[(wr + mi * 16 + lr) * 64 + ko];
#pragma unroll
      for (int ni = 0; ni < 4; ++ni) bq[ni] = *(const short8*)&Bs[(wc + ni * 16 + lr) * 64 + ko];
#pragma unroll
      for (int mi = 0; mi < 4; ++mi)
#pragma unroll
        for (int ni = 0; ni < 4; ++ni) acc[mi][ni] = MFMA16(a[mi], bq[ni], acc[mi][ni]);
    }
    __syncthreads();
  }
  const int row0 = mt * 128 + wr + lg * 4;  // + mi*16 + r
  const int col0 = nt * 128 + wc + lr;      // + ni*16

  if constexpr (EPI == 0) {
    // scatter into q/k/v [win][head][64][32]; q scaled by 32^-0.5
#pragma unroll
    for (int mi = 0; mi < 4; ++mi)
#pragma unroll
      for (int ni = 0; ni < 4; ++ni) {
        const int col = col0 + ni * 16;
        const int which = col >> 8, cc = col & 255;
        const int head = cc >> 5, hd = cc & 31;
        u16* dst = outh + (size_t)which * 16777216ull;
        const float scl = (which == 0) ? 0.17677669529663689f : 1.0f;
        const float bv = bias[col];
#pragma unroll
        for (int r = 0; r < 4; ++r) {
          const int row = row0 + mi * 16 + r;
          const int win = row >> 6, tk = row & 63;
          dst[(((size_t)(win * 8 + head) << 6) + tk) * 32 + hd] =
              f2b((acc[mi][ni][r] + bv) * scl);
        }
      }
  } else if constexpr (EPI == 1) {
#pragma unroll
    for (int mi = 0; mi < 4; ++mi)
#pragma unroll
      for (int ni = 0; ni < 4; ++ni) {
        const int col = col0 + ni * 16;
        const float bv = bias[col];
#pragma unroll
        for (int r = 0; r < 4; ++r) {
          const int row = row0 + mi * 16 + r;
          const int win = row >> 6, tk = row & 63;
          const int bb = win >> 6;
          const int h = (((win >> 3) & 7) << 3) + (tk >> 3);
          const int w = ((win & 7) << 3) + (tk & 7);
          float val = acc[mi][ni][r] + bv +
                      aux[(((size_t)bb * 256 + col) * 64 + h) * 64 + w];
          outf[(size_t)row * 256 + col] = val;
        }
      }
  } else if constexpr (EPI == 2) {
#pragma unroll
    for (int mi = 0; mi < 4; ++mi)
#pragma unroll
      for (int ni = 0; ni < 4; ++ni) {
        const int col = col0 + ni * 16;
        const float bv = bias[col];
#pragma unroll
        for (int r = 0; r < 4; ++r) {
          const int row = row0 + mi * 16 + r;
          float val = acc[mi][ni][r] + bv;
          float gl = 0.5f * val * (1.0f + erff(val * 0.70710678118654752f));
          outh[(size_t)row * N + col] = f2b(gl);
        }
      }
  } else {  // EPI == 3
#pragma unroll
    for (int mi = 0; mi < 4; ++mi)
#pragma unroll
      for (int ni = 0; ni < 4; ++ni) {
        const int col = col0 + ni * 16;
        const float bv = bias[col];
        const int row = row0 + mi * 16;  // rows row..row+3 are 4 consecutive w
        const int win = row >> 6, tk = row & 63;
        const int bb = win >> 6;
        const int h = (((win >> 3) & 7) << 3) + (tk >> 3);
        const int w = ((win & 7) << 3) + (tk & 7);
        f32x4 v;
#pragma unroll
        for (int r = 0; r < 4; ++r)
          v[r] = acc[mi][ni][r] + bv + aux[(size_t)(row + r) * 256 + col];
        *(f32x4*)&outf[(((size_t)bb * 256 + col) * 64 + h) * 64 + w] = v;
      }
  }
}

// ---------------- K3: windowed attention, 1 wave per (window, head) ----------------
__global__ __launch_bounds__(64) void attn_kernel(const u16* __restrict__ qkv,
                                                  const float* __restrict__ biasf,
                                                  u16* __restrict__ aout) {
  __shared__ __align__(16) u16 qs[64 * 40];
  __shared__ __align__(16) u16 ks[64 * 40];
  __shared__ __align__(16) u16 vt[32 * 72];  // v transposed [hd][m]
  __shared__ __align__(16) u16 pp[64 * 72];  // softmax probs [n][m]
  const int wh = blockIdx.x;  // win*8 + head
  const int head = wh & 7;
  const int win = wh >> 3;
  const int lane = threadIdx.x;
  const int lr = lane & 15, lg = lane >> 4;
  const u16* qg = qkv + (size_t)wh * 2048;
  const u16* kg = qkv + 16777216ull + (size_t)wh * 2048;
  const u16* vg = qkv + 33554432ull + (size_t)wh * 2048;
#pragma unroll
  for (int i = 0; i < 4; ++i) {
    int ch = i * 64 + lane;
    int r = ch >> 2, qo = (ch & 3) * 8;
    *(short8*)&qs[r * 40 + qo] = *(const short8*)&qg[r * 32 + qo];
    *(short8*)&ks[r * 40 + qo] = *(const short8*)&kg[r * 32 + qo];
  }
  {
    short8 v0 = *(const short8*)&vg[(size_t)lane * 32];
    short8 v1 = *(const short8*)&vg[(size_t)lane * 32 + 8];
    short8 v2 = *(const short8*)&vg[(size_t)lane * 32 + 16];
    short8 v3 = *(const short8*)&vg[(size_t)lane * 32 + 24];
#pragma unroll
    for (int j = 0; j < 8; ++j) {
      vt[j * 72 + lane] = (u16)v0[j];
      vt[(8 + j) * 72 + lane] = (u16)v1[j];
      vt[(16 + j) * 72 + lane] = (u16)v2[j];
      vt[(24 + j) * 72 + lane] = (u16)v3[j];
    }
  }
  __syncthreads();
  f32x4 sf[4][4];
#pragma unroll
  for (int mi = 0; mi < 4; ++mi)
#pragma unroll
    for (int ni = 0; ni < 4; ++ni) sf[mi][ni] = (f32x4){0.f, 0.f, 0.f, 0.f};
  {
    short8 a[4], bq[4];
#pragma unroll
    for (int mi = 0; mi < 4; ++mi) a[mi] = *(const short8*)&qs[(mi * 16 + lr) * 40 + lg * 8];
#pragma unroll
    for (int ni = 0; ni < 4; ++ni) bq[ni] = *(const short8*)&ks[(ni * 16 + lr) * 40 + lg * 8];
#pragma unroll
    for (int mi = 0; mi < 4; ++mi)
#pragma unroll
      for (int ni = 0; ni < 4; ++ni) sf[mi][ni] = MFMA16(a[mi], bq[ni], sf[mi][ni]);
  }
  const float* bh = biasf + (size_t)head * 4096;
#pragma unroll
  for (int mi = 0; mi < 4; ++mi) {
#pragma unroll
    for (int r = 0; r < 4; ++r) {
      const int n = mi * 16 + lg * 4 + r;
      float v0 = sf[mi][0][r] + bh[n * 64 + lr];
      float v1 = sf[mi][1][r] + bh[n * 64 + 16 + lr];
      float v2 = sf[mi][2][r] + bh[n * 64 + 32 + lr];
      float v3 = sf[mi][3][r] + bh[n * 64 + 48 + lr];
      float mx = fmaxf(fmaxf(v0, v1), fmaxf(v2, v3));
      mx = fmaxf(mx, __shfl_xor(mx, 1));
      mx = fmaxf(mx, __shfl_xor(mx, 2));
      mx = fmaxf(mx, __shfl_xor(mx, 4));
      mx = fmaxf(mx, __shfl_xor(mx, 8));
      float e0 = __expf(v0 - mx), e1 = __expf(v1 - mx);
      float e2 = __expf(v2 - mx), e3 = __expf(v3 - mx);
      float sm = e0 + e1 + e2 + e3;
      sm += __shfl_xor(sm, 1);
      sm += __shfl_xor(sm, 2);
      sm += __shfl_xor(sm, 4);
      sm += __shfl_xor(sm, 8);
      const float inv = 1.f / sm;
      pp[n * 72 + lr] = f2b(e0 * inv);
      pp[n * 72 + 16 + lr] = f2b(e1 * inv);
      pp[n * 72 + 32 + lr] = f2b(e2 * inv);
      pp[n * 72 + 48 + lr] = f2b(e3 * inv);
    }
  }
  __syncthreads();
  f32x4 o[4][2];
#pragma unroll
  for (int mi = 0; mi < 4; ++mi)
#pragma unroll
    for (int ni = 0; ni < 2; ++ni) o[mi][ni] = (f32x4){0.f, 0.f, 0.f, 0.f};
#pragma unroll
  for (int kk = 0; kk < 2; ++kk) {
    short8 pa[4], vb[2];
#pragma unroll
    for (int mi = 0; mi < 4; ++mi)
      pa[mi] = *(const short8*)&pp[(mi * 16 + lr) * 72 + kk * 32 + lg * 8];
#pragma unroll
    for (int ni = 0; ni < 2; ++ni)
      vb[ni] = *(const short8*)&vt[(ni * 16 + lr) * 72 + kk * 32 + lg * 8];
#pragma unroll
    for (int mi = 0; mi < 4; ++mi)
#pragma unroll
      for (int ni = 0; ni < 2; ++ni) o[mi][ni] = MFMA16(pa[mi], vb[ni], o[mi][ni]);
  }
  u16* op = aout + (size_t)win * 16384 + head * 32;
#pragma unroll
  for (int mi = 0; mi < 4; ++mi)
#pragma unroll
    for (int ni = 0; ni < 2; ++ni)
#pragma unroll
      for (int r = 0; r < 4; ++r) {
        const int n = mi * 16 + lg * 4 + r;
        op[(size_t)n * 256 + ni * 16 + lr] = f2b(o[mi][ni][r]);
      }
}

// ---------------- K5: LN2, one wave per row ----------------
__global__ __launch_bounds__(256) void ln2_kernel(const float* __restrict__ xs2,
                                                  const float* __restrict__ g,
                                                  const float* __restrict__ b,
                                                  u16* __restrict__ h2) {
  const int wv = threadIdx.x >> 6, lane = threadIdx.x & 63;
  const size_t row = (size_t)blockIdx.x * 4 + wv;
  const f32x4 xv = *(const f32x4*)&xs2[row * 256 + lane * 4];
  float s = xv[0] + xv[1] + xv[2] + xv[3];
  float q = xv[0] * xv[0] + xv[1] * xv[1] + xv[2] * xv[2] + xv[3] * xv[3];
#pragma unroll
  for (int off = 1; off < 64; off <<= 1) {
    s += __shfl_xor(s, off);
    q += __shfl_xor(q, off);
  }
  const float m = s * (1.f / 256.f);
  const float rstd = rsqrtf(q * (1.f / 256.f) - m * m + 1e-5f);
  const f32x4 gv = *(const f32x4*)&g[lane * 4];
  const f32x4 bv = *(const f32x4*)&b[lane * 4];
  union {
    u16 u[4];
    unsigned long long v;
  } pk;
#pragma unroll
  for (int j = 0; j < 4; ++j) pk.u[j] = f2b((xv[j] - m) * rstd * gv[j] + bv[j]);
  *(unsigned long long*)&h2[row * 256 + lane * 4] = pk.v;
}

extern "C" void kernel_launch(void* const* d_in, const int* in_sizes, int n_in,
                              void* d_out, int out_size, void* d_ws, size_t ws_size,
                              hipStream_t stream) {
  const float* x = (const float*)d_in[0];
  const float* n1g = (const float*)d_in[1];
  const float* n1b = (const float*)d_in[2];
  const float* qkv_w = (const float*)d_in[3];
  const float* qkv_b = (const float*)d_in[4];
  const float* tbl = (const float*)d_in[5];
  const float* proj_w = (const float*)d_in[6];
  const float* proj_b = (const float*)d_in[7];
  const float* n2g = (const float*)d_in[8];
  const float* n2b = (const float*)d_in[9];
  const float* fc1_w = (const float*)d_in[10];
  const float* fc1_b = (const float*)d_in[11];
  const float* fc2_w = (const float*)d_in[12];
  const float* fc2_b = (const float*)d_in[13];
  const int* relidx = (const int*)d_in[14];
  float* outp = (float*)d_out;

  char* w = (char*)d_ws;
  const size_t Mi = 1ull << 20;
  // ws timeline (reuse): [0,32Mi): Y -> attn_out -> h2 ; [32,96Mi): q,k -> xs2 ;
  // [96,224Mi): v (first 32Mi) -> h1 ; [224Mi..): bf16 weights + bias table.
  if (ws_size < 237 * Mi) return;  // insufficient scratch; leave output poisoned
  u16* Y = (u16*)(w + 0);
  u16* qb = (u16*)(w + 32 * Mi);  // q,k,v each 16777216 elems (32 MiB)
  u16* aout = (u16*)(w + 0);
  float* xs2 = (float*)(w + 32 * Mi);
  u16* h2 = (u16*)(w + 0);
  u16* h1 = (u16*)(w + 96 * Mi);
  u16* wqkv = (u16*)(w + 224 * Mi);
  u16* wproj = wqkv + 196608;
  u16* wfc1 = wproj + 65536;
  u16* wfc2 = wfc1 + 262144;
  float* bfull = (float*)(w + 224 * Mi + 1572864);

  f2bf_kernel<<<768, 256, 0, stream>>>(qkv_w, wqkv, 196608);
  f2bf_kernel<<<256, 256, 0, stream>>>(proj_w, wproj, 65536);
  f2bf_kernel<<<1024, 256, 0, stream>>>(fc1_w, wfc1, 262144);
  f2bf_kernel<<<1024, 256, 0, stream>>>(fc2_w, wfc2, 262144);
  biasfull_kernel<<<128, 256, 0, stream>>>(tbl, relidx, bfull);

  ln1_win_kernel<<<1024, 256, 0, stream>>>(x, n1g, n1b, Y);
  gemm_bt<0><<<512 * 6, 256, 0, stream>>>(Y, wqkv, qkv_b, qb, nullptr, nullptr, 768, 256);
  attn_kernel<<<8192, 64, 0, stream>>>(qb, bfull, aout);
  gemm_bt<1><<<512 * 2, 256, 0, stream>>>(aout, wproj, proj_b, nullptr, xs2, x, 256, 256);
  ln2_kernel<<<16384, 256, 0, stream>>>(xs2, n2g, n2b, h2);
  gemm_bt<2><<<512 * 8, 256, 0, stream>>>(h2, wfc1, fc1_b, h1, nullptr, nullptr, 1024, 256);
  gemm_bt<3><<<512 * 2, 256, 0, stream>>>(h1, wfc2, fc2_b, nullptr, outp, xs2, 256, 1024);
}

// Round 2
// 373.691 us; speedup vs baseline: 1.1253x; 1.1253x over previous
//
#include <hip/hip_runtime.h>

typedef unsigned short u16;
typedef __attribute__((ext_vector_type(8))) short short8;
typedef __attribute__((ext_vector_type(4))) float f32x4;

#define MFMA16(a, b, c) __builtin_amdgcn_mfma_f32_16x16x32_bf16((a), (b), (c), 0, 0, 0)

__device__ __forceinline__ u16 f2b(float f) {
  unsigned b = __float_as_uint(f);
  b += 0x7FFFu + ((b >> 16) & 1u);
  return (u16)(b >> 16);
}

__device__ __forceinline__ void gload_lds16(const void* g, void* l) {
  __builtin_amdgcn_global_load_lds((const __attribute__((address_space(1))) void*)g,
                                   (__attribute__((address_space(3))) void*)l, 16, 0, 0);
}

// fast exact-enough GELU: erf via Abramowitz-Stegun 7.1.26 (|err|<=1.5e-7)
__device__ __forceinline__ float fast_gelu(float x) {
  const float u = x * 0.70710678118654752f;
  const float au = fabsf(u);
  float d = 1.f + 0.3275911f * au;
  float tt;
  asm("v_rcp_f32 %0, %1" : "=v"(tt) : "v"(d));
  float p = 1.061405429f * tt - 1.453152027f;
  p = p * tt + 1.421413741f;
  p = p * tt - 0.284496736f;
  p = p * tt + 0.254829592f;
  p = p * tt;
  const float e = __expf(-u * u);
  const float erf_au = 1.f - p * e;
  return 0.5f * x * (1.f + copysignf(erf_au, x));
}

// ---------------- small setup kernels ----------------
__global__ __launch_bounds__(256) void f2bf_kernel(const float* __restrict__ s,
                                                   u16* __restrict__ d, int n) {
  int i = blockIdx.x * 256 + threadIdx.x;
  if (i < n) d[i] = f2b(s[i]);
}

// bias_full[h][n][m] = table[rel_index[n*64+m]*8 + h], 8*4096 entries
__global__ __launch_bounds__(256) void biasfull_kernel(const float* __restrict__ tbl,
                                                       const int* __restrict__ ridx,
                                                       float* __restrict__ o) {
  int i = blockIdx.x * 256 + threadIdx.x;
  int hm = i >> 12, nm = i & 4095;
  o[i] = tbl[ridx[nm] * 8 + hm];
}

// ---------------- K1: LN1 + window partition -> Y bf16 [65536][256] ----------------
// block = (b, h) image row; lane = w (coalesced reads); wave = 64-channel group
__global__ __launch_bounds__(256) void ln1_win_kernel(const float* __restrict__ x,
                                                      const float* __restrict__ g,
                                                      const float* __restrict__ b,
                                                      u16* __restrict__ y) {
  __shared__ float red[2][4][64];
  const int bh = blockIdx.x;  // b*64 + h
  const int bb = bh >> 6, h = bh & 63;
  const int w = threadIdx.x & 63, cg = threadIdx.x >> 6;
  const float* xp = x + (size_t)bb * 1048576 + (size_t)h * 64 + w;
  float vals[64];
  float s = 0.f, ss = 0.f;
#pragma unroll
  for (int j = 0; j < 64; ++j) {
    float v = xp[(size_t)(cg * 64 + j) * 4096];
    vals[j] = v;
    s += v;
    ss += v * v;
  }
  red[0][cg][w] = s;
  red[1][cg][w] = ss;
  __syncthreads();
  const float S = red[0][0][w] + red[0][1][w] + red[0][2][w] + red[0][3][w];
  const float Q = red[1][0][w] + red[1][1][w] + red[1][2][w] + red[1][3][w];
  const float m = S * (1.f / 256.f);
  const float rstd = rsqrtf(Q * (1.f / 256.f) - m * m + 1e-5f);
  const int win = bb * 64 + ((h >> 3) << 3) + (w >> 3);
  const int tok = ((h & 7) << 3) + (w & 7);
  u16* yp = y + (size_t)win * 16384 + tok * 256 + cg * 64;
#pragma unroll
  for (int jj = 0; jj < 8; ++jj) {
    short8 o;
#pragma unroll
    for (int q = 0; q < 8; ++q) {
      const int c64 = jj * 8 + q;
      const int c = cg * 64 + c64;
      o[q] = (short)f2b((vals[c64] - m) * rstd * g[c] + b[c]);
    }
    *(short8*)&yp[jj * 8] = o;
  }
}

// ---------------- GEMM: out = A[M x K] * W[N x K]^T + bias, bf16 MFMA ----------------
// 2-phase double-buffered pipeline (T3 minimum recipe) + T2 swizzle via
// pre-swizzled global source (LDS dest stays linear for global_load_lds).
// EPI 0: qkv scatter (+q scale).  1: proj + x residual -> xs2 fp32.
// EPI 2: fc1 + fast GELU -> bf16. 3: fc2 + xs2 residual -> d_out BCHW fp32.
template <int EPI>
__global__ __launch_bounds__(256) void gemm_bt(const u16* __restrict__ A,
                                               const u16* __restrict__ W,
                                               const float* __restrict__ bias,
                                               u16* __restrict__ outh,
                                               float* __restrict__ outf,
                                               const float* __restrict__ aux,
                                               const int N, const int K) {
  __shared__ __align__(16) u16 As[2][128 * 64];
  __shared__ __align__(16) u16 Bs[2][128 * 64];
  const int ntiles = N >> 7;
  const int mt = blockIdx.x / ntiles;
  const int nt = blockIdx.x - mt * ntiles;
  const int tid = threadIdx.x;
  const int wv = tid >> 6, lane = tid & 63;
  const int wr = (wv >> 1) << 6;  // wave row quadrant
  const int wc = (wv & 1) << 6;   // wave col quadrant
  const int lrow = lane >> 3;
  const int lkswz = (((lane & 7) ^ (lane >> 3)) << 3);  // swizzled source k-offset
  const int lr = lane & 15, lg = lane >> 4;
  const int swz = (lr & 7) << 3;  // read-side XOR (row&7)<<3, row&7 == lr&7 here
  f32x4 acc[4][4];
#pragma unroll
  for (int mi = 0; mi < 4; ++mi)
#pragma unroll
    for (int ni = 0; ni < 4; ++ni) acc[mi][ni] = (f32x4){0.f, 0.f, 0.f, 0.f};
  const u16* Ab = A + (size_t)mt * 128 * K;
  const u16* Wb = W + (size_t)nt * 128 * K;
  const int ntk = K >> 6;

  auto STAGE = [&](int bf, int t) {
    const int kt = t << 6;
#pragma unroll
    for (int i = 0; i < 4; ++i) {
      const int rb = wv * 32 + i * 8;
      gload_lds16(Ab + (size_t)(rb + lrow) * K + kt + lkswz, &As[bf][rb * 64]);
    }
#pragma unroll
    for (int i = 0; i < 4; ++i) {
      const int rb = wv * 32 + i * 8;
      gload_lds16(Wb + (size_t)(rb + lrow) * K + kt + lkswz, &Bs[bf][rb * 64]);
    }
  };

  STAGE(0, 0);
  __syncthreads();  // tile 0 resident (vmcnt(0) drained by syncthreads)
  int cur = 0;
  for (int t = 0; t < ntk; ++t) {
    if (t + 1 < ntk) STAGE(cur ^ 1, t + 1);  // issue next tile; flies under MFMA
#pragma unroll
    for (int kk = 0; kk < 2; ++kk) {
      const int kq = (kk * 32 + lg * 8) ^ swz;
      short8 a[4], bq[4];
#pragma unroll
      for (int mi = 0; mi < 4; ++mi)
        a[mi] = *(const short8*)&As[cur][(wr + mi * 16 + lr) * 64 + kq];
#pragma unroll
      for (int ni = 0; ni < 4; ++ni)
        bq[ni] = *(const short8*)&Bs[cur][(wc + ni * 16 + lr) * 64 + kq];
#pragma unroll
      for (int mi = 0; mi < 4; ++mi)
#pragma unroll
        for (int ni = 0; ni < 4; ++ni) acc[mi][ni] = MFMA16(a[mi], bq[ni], acc[mi][ni]);
    }
    __syncthreads();  // drains next-tile vmcnt + all waves done reading cur
    cur ^= 1;
  }
  const int row0 = mt * 128 + wr + lg * 4;  // + mi*16 + r
  const int col0 = nt * 128 + wc + lr;      // + ni*16

  if constexpr (EPI == 0) {
    // scatter into q/k/v [win][head][64][32]; q scaled by 32^-0.5
#pragma unroll
    for (int mi = 0; mi < 4; ++mi)
#pragma unroll
      for (int ni = 0; ni < 4; ++ni) {
        const int col = col0 + ni * 16;
        const int which = col >> 8, cc = col & 255;
        const int head = cc >> 5, hd = cc & 31;
        u16* dst = outh + (size_t)which * 16777216ull;
        const float scl = (which == 0) ? 0.17677669529663689f : 1.0f;
        const float bv = bias[col];
#pragma unroll
        for (int r = 0; r < 4; ++r) {
          const int row = row0 + mi * 16 + r;
          const int win = row >> 6, tk = row & 63;
          dst[(((size_t)(win * 8 + head) << 6) + tk) * 32 + hd] =
              f2b((acc[mi][ni][r] + bv) * scl);
        }
      }
  } else if constexpr (EPI == 1) {
#pragma unroll
    for (int mi = 0; mi < 4; ++mi)
#pragma unroll
      for (int ni = 0; ni < 4; ++ni) {
        const int col = col0 + ni * 16;
        const float bv = bias[col];
#pragma unroll
        for (int r = 0; r < 4; ++r) {
          const int row = row0 + mi * 16 + r;
          const int win = row >> 6, tk = row & 63;
          const int bb = win >> 6;
          const int h = (((win >> 3) & 7) << 3) + (tk >> 3);
          const int w = ((win & 7) << 3) + (tk & 7);
          float val = acc[mi][ni][r] + bv +
                      aux[(((size_t)bb * 256 + col) * 64 + h) * 64 + w];
          outf[(size_t)row * 256 + col] = val;
        }
      }
  } else if constexpr (EPI == 2) {
#pragma unroll
    for (int mi = 0; mi < 4; ++mi)
#pragma unroll
      for (int ni = 0; ni < 4; ++ni) {
        const int col = col0 + ni * 16;
        const float bv = bias[col];
#pragma unroll
        for (int r = 0; r < 4; ++r) {
          const int row = row0 + mi * 16 + r;
          outh[(size_t)row * N + col] = f2b(fast_gelu(acc[mi][ni][r] + bv));
        }
      }
  } else {  // EPI == 3
#pragma unroll
    for (int mi = 0; mi < 4; ++mi)
#pragma unroll
      for (int ni = 0; ni < 4; ++ni) {
        const int col = col0 + ni * 16;
        const float bv = bias[col];
        const int row = row0 + mi * 16;  // rows row..row+3 are 4 consecutive w
        const int win = row >> 6, tk = row & 63;
        const int bb = win >> 6;
        const int h = (((win >> 3) & 7) << 3) + (tk >> 3);
        const int w = ((win & 7) << 3) + (tk & 7);
        f32x4 v;
#pragma unroll
        for (int r = 0; r < 4; ++r)
          v[r] = acc[mi][ni][r] + bv + aux[(size_t)(row + r) * 256 + col];
        *(f32x4*)&outf[(((size_t)bb * 256 + col) * 64 + h) * 64 + w] = v;
      }
  }
}

// ---------------- K3: windowed attention, 1 wave per (window, head) ----------------
__global__ __launch_bounds__(64) void attn_kernel(const u16* __restrict__ qkv,
                                                  const float* __restrict__ biasf,
                                                  u16* __restrict__ aout) {
  __shared__ __align__(16) u16 qs[64 * 40];
  __shared__ __align__(16) u16 ks[64 * 40];
  __shared__ __align__(16) u16 vt[32 * 72];  // v transposed [hd][m]
  __shared__ __align__(16) u16 pp[64 * 72];  // softmax probs [n][m]
  const int wh = blockIdx.x;  // win*8 + head
  const int head = wh & 7;
  const int win = wh >> 3;
  const int lane = threadIdx.x;
  const int lr = lane & 15, lg = lane >> 4;
  const u16* qg = qkv + (size_t)wh * 2048;
  const u16* kg = qkv + 16777216ull + (size_t)wh * 2048;
  const u16* vg = qkv + 33554432ull + (size_t)wh * 2048;
#pragma unroll
  for (int i = 0; i < 4; ++i) {
    int ch = i * 64 + lane;
    int r = ch >> 2, qo = (ch & 3) * 8;
    *(short8*)&qs[r * 40 + qo] = *(const short8*)&qg[r * 32 + qo];
    *(short8*)&ks[r * 40 + qo] = *(const short8*)&kg[r * 32 + qo];
  }
  {
    short8 v0 = *(const short8*)&vg[(size_t)lane * 32];
    short8 v1 = *(const short8*)&vg[(size_t)lane * 32 + 8];
    short8 v2 = *(const short8*)&vg[(size_t)lane * 32 + 16];
    short8 v3 = *(const short8*)&vg[(size_t)lane * 32 + 24];
#pragma unroll
    for (int j = 0; j < 8; ++j) {
      vt[j * 72 + lane] = (u16)v0[j];
      vt[(8 + j) * 72 + lane] = (u16)v1[j];
      vt[(16 + j) * 72 + lane] = (u16)v2[j];
      vt[(24 + j) * 72 + lane] = (u16)v3[j];
    }
  }
  __syncthreads();
  f32x4 sf[4][4];
#pragma unroll
  for (int mi = 0; mi < 4; ++mi)
#pragma unroll
    for (int ni = 0; ni < 4; ++ni) sf[mi][ni] = (f32x4){0.f, 0.f, 0.f, 0.f};
  {
    short8 a[4], bq[4];
#pragma unroll
    for (int mi = 0; mi < 4; ++mi) a[mi] = *(const short8*)&qs[(mi * 16 + lr) * 40 + lg * 8];
#pragma unroll
    for (int ni = 0; ni < 4; ++ni) bq[ni] = *(const short8*)&ks[(ni * 16 + lr) * 40 + lg * 8];
#pragma unroll
    for (int mi = 0; mi < 4; ++mi)
#pragma unroll
      for (int ni = 0; ni < 4; ++ni) sf[mi][ni] = MFMA16(a[mi], bq[ni], sf[mi][ni]);
  }
  const float* bh = biasf + (size_t)head * 4096;
#pragma unroll
  for (int mi = 0; mi < 4; ++mi) {
#pragma unroll
    for (int r = 0; r < 4; ++r) {
      const int n = mi * 16 + lg * 4 + r;
      float v0 = sf[mi][0][r] + bh[n * 64 + lr];
      float v1 = sf[mi][1][r] + bh[n * 64 + 16 + lr];
      float v2 = sf[mi][2][r] + bh[n * 64 + 32 + lr];
      float v3 = sf[mi][3][r] + bh[n * 64 + 48 + lr];
      float mx = fmaxf(fmaxf(v0, v1), fmaxf(v2, v3));
      mx = fmaxf(mx, __shfl_xor(mx, 1));
      mx = fmaxf(mx, __shfl_xor(mx, 2));
      mx = fmaxf(mx, __shfl_xor(mx, 4));
      mx = fmaxf(mx, __shfl_xor(mx, 8));
      float e0 = __expf(v0 - mx), e1 = __expf(v1 - mx);
      float e2 = __expf(v2 - mx), e3 = __expf(v3 - mx);
      float sm = e0 + e1 + e2 + e3;
      sm += __shfl_xor(sm, 1);
      sm += __shfl_xor(sm, 2);
      sm += __shfl_xor(sm, 4);
      sm += __shfl_xor(sm, 8);
      const float inv = 1.f / sm;
      pp[n * 72 + lr] = f2b(e0 * inv);
      pp[n * 72 + 16 + lr] = f2b(e1 * inv);
      pp[n * 72 + 32 + lr] = f2b(e2 * inv);
      pp[n * 72 + 48 + lr] = f2b(e3 * inv);
    }
  }
  __syncthreads();
  f32x4 o[4][2];
#pragma unroll
  for (int mi = 0; mi < 4; ++mi)
#pragma unroll
    for (int ni = 0; ni < 2; ++ni) o[mi][ni] = (f32x4){0.f, 0.f, 0.f, 0.f};
#pragma unroll
  for (int kk = 0; kk < 2; ++kk) {
    short8 pa[4], vb[2];
#pragma unroll
    for (int mi = 0; mi < 4; ++mi)
      pa[mi] = *(const short8*)&pp[(mi * 16 + lr) * 72 + kk * 32 + lg * 8];
#pragma unroll
    for (int ni = 0; ni < 2; ++ni)
      vb[ni] = *(const short8*)&vt[(ni * 16 + lr) * 72 + kk * 32 + lg * 8];
#pragma unroll
    for (int mi = 0; mi < 4; ++mi)
#pragma unroll
      for (int ni = 0; ni < 2; ++ni) o[mi][ni] = MFMA16(pa[mi], vb[ni], o[mi][ni]);
  }
  u16* op = aout + (size_t)win * 16384 + head * 32;
#pragma unroll
  for (int mi = 0; mi < 4; ++mi)
#pragma unroll
    for (int ni = 0; ni < 2; ++ni)
#pragma unroll
      for (int r = 0; r < 4; ++r) {
        const int n = mi * 16 + lg * 4 + r;
        op[(size_t)n * 256 + ni * 16 + lr] = f2b(o[mi][ni][r]);
      }
}

// ---------------- K5: LN2, one wave per row ----------------
__global__ __launch_bounds__(256) void ln2_kernel(const float* __restrict__ xs2,
                                                  const float* __restrict__ g,
                                                  const float* __restrict__ b,
                                                  u16* __restrict__ h2) {
  const int wv = threadIdx.x >> 6, lane = threadIdx.x & 63;
  const size_t row = (size_t)blockIdx.x * 4 + wv;
  const f32x4 xv = *(const f32x4*)&xs2[row * 256 + lane * 4];
  float s = xv[0] + xv[1] + xv[2] + xv[3];
  float q = xv[0] * xv[0] + xv[1] * xv[1] + xv[2] * xv[2] + xv[3] * xv[3];
#pragma unroll
  for (int off = 1; off < 64; off <<= 1) {
    s += __shfl_xor(s, off);
    q += __shfl_xor(q, off);
  }
  const float m = s * (1.f / 256.f);
  const float rstd = rsqrtf(q * (1.f / 256.f) - m * m + 1e-5f);
  const f32x4 gv = *(const f32x4*)&g[lane * 4];
  const f32x4 bv = *(const f32x4*)&b[lane * 4];
  union {
    u16 u[4];
    unsigned long long v;
  } pk;
#pragma unroll
  for (int j = 0; j < 4; ++j) pk.u[j] = f2b((xv[j] - m) * rstd * gv[j] + bv[j]);
  *(unsigned long long*)&h2[row * 256 + lane * 4] = pk.v;
}

extern "C" void kernel_launch(void* const* d_in, const int* in_sizes, int n_in,
                              void* d_out, int out_size, void* d_ws, size_t ws_size,
                              hipStream_t stream) {
  const float* x = (const float*)d_in[0];
  const float* n1g = (const float*)d_in[1];
  const float* n1b = (const float*)d_in[2];
  const float* qkv_w = (const float*)d_in[3];
  const float* qkv_b = (const float*)d_in[4];
  const float* tbl = (const float*)d_in[5];
  const float* proj_w = (const float*)d_in[6];
  const float* proj_b = (const float*)d_in[7];
  const float* n2g = (const float*)d_in[8];
  const float* n2b = (const float*)d_in[9];
  const float* fc1_w = (const float*)d_in[10];
  const float* fc1_b = (const float*)d_in[11];
  const float* fc2_w = (const float*)d_in[12];
  const float* fc2_b = (const float*)d_in[13];
  const int* relidx = (const int*)d_in[14];
  float* outp = (float*)d_out;

  char* w = (char*)d_ws;
  const size_t Mi = 1ull << 20;
  // ws timeline (reuse): [0,32Mi): Y -> attn_out -> h2 ; [32,96Mi): q,k -> xs2 ;
  // [96,224Mi): v (first 32Mi) -> h1 ; [224Mi..): bf16 weights + bias table.
  if (ws_size < 237 * Mi) return;  // insufficient scratch; leave output poisoned
  u16* Y = (u16*)(w + 0);
  u16* qb = (u16*)(w + 32 * Mi);  // q,k,v each 16777216 elems (32 MiB)
  u16* aout = (u16*)(w + 0);
  float* xs2 = (float*)(w + 32 * Mi);
  u16* h2 = (u16*)(w + 0);
  u16* h1 = (u16*)(w + 96 * Mi);
  u16* wqkv = (u16*)(w + 224 * Mi);
  u16* wproj = wqkv + 196608;
  u16* wfc1 = wproj + 65536;
  u16* wfc2 = wfc1 + 262144;
  float* bfull = (float*)(w + 224 * Mi + 1572864);

  f2bf_kernel<<<768, 256, 0, stream>>>(qkv_w, wqkv, 196608);
  f2bf_kernel<<<256, 256, 0, stream>>>(proj_w, wproj, 65536);
  f2bf_kernel<<<1024, 256, 0, stream>>>(fc1_w, wfc1, 262144);
  f2bf_kernel<<<1024, 256, 0, stream>>>(fc2_w, wfc2, 262144);
  biasfull_kernel<<<128, 256, 0, stream>>>(tbl, relidx, bfull);

  ln1_win_kernel<<<1024, 256, 0, stream>>>(x, n1g, n1b, Y);
  gemm_bt<0><<<512 * 6, 256, 0, stream>>>(Y, wqkv, qkv_b, qb, nullptr, nullptr, 768, 256);
  attn_kernel<<<8192, 64, 0, stream>>>(qb, bfull, aout);
  gemm_bt<1><<<512 * 2, 256, 0, stream>>>(aout, wproj, proj_b, nullptr, xs2, x, 256, 256);
  ln2_kernel<<<16384, 256, 0, stream>>>(xs2, n2g, n2b, h2);
  gemm_bt<2><<<512 * 8, 256, 0, stream>>>(h2, wfc1, fc1_b, h1, nullptr, nullptr, 1024, 256);
  gemm_bt<3><<<512 * 2, 256, 0, stream>>>(h1, wfc2, fc2_b, nullptr, outp, xs2, 256, 1024);
}